// Round 5
// baseline (281.262 us; speedup 1.0000x reference)
//
#include <hip/hip_runtime.h>
#include <hip/hip_bf16.h>

typedef __attribute__((ext_vector_type(8))) short short8;
typedef __attribute__((ext_vector_type(4))) float f32x4;

#define NTOK   100000
#define H      150
#define KSEG   160        // padded per-matrix K in wb
#define KTOT   640        // 4 * KSEG
#define BM     64         // rows per block
#define LROW   152        // padded LDS row (bf16 elems) = 304B: 16B-aligned, conflict-free
#define SEGSZ  (BM * LROW)   // 9728 bf16 elems per segment
#define OUTOFF (NTOK * H)

__device__ __forceinline__ unsigned short f2bf(float f) {
    unsigned int u = __builtin_bit_cast(unsigned int, f);
    u = (u + 0x7FFFu + ((u >> 16) & 1u)) >> 16;   // RNE
    return (unsigned short)u;
}

// ---------------------------------------------------------------------------
// Prepass: pack 4x [150,150] fp32 weights into wb[c][k] bf16, c in [0,160),
// k in [0,640) stacked (w_in | w_out | u_in | u_out), zero-padded.
// wb[c][k] = W_seg[k%160][c]
// ---------------------------------------------------------------------------
__global__ void prep_w(const float* __restrict__ w_in, const float* __restrict__ w_out,
                       const float* __restrict__ u_in, const float* __restrict__ u_out,
                       unsigned short* __restrict__ wb) {
    int idx = blockIdx.x * 256 + threadIdx.x;
    if (idx >= 160 * KTOT) return;
    int c = idx / KTOT;
    int k = idx % KTOT;
    int seg = k / KSEG;
    int k2  = k % KSEG;
    float v = 0.0f;
    if (c < H && k2 < H) {
        const float* W = (seg == 0) ? w_in : (seg == 1) ? w_out : (seg == 2) ? u_in : u_out;
        v = W[k2 * H + c];
    }
    wb[idx] = f2bf(v);
}

// ---------------------------------------------------------------------------
// Main fused kernel. Per block: 64 rows x 160 cols.
// Phase 1: stage ALL of the block's X (4 segs x 64 rows x 150) into LDS as
//          bf16 via coalesced float2 streams (block's X region is contiguous).
// Phase 2: ONE barrier, then 20 K-steps of pure LDS-read + L2-weight-read +
//          MFMA, no further barriers.
// 4 waves (2M x 2N): each wave 32 rows x 80 cols = 2x5 frags of 16x16.
// ---------------------------------------------------------------------------
__global__ __launch_bounds__(256) void lstm_fused(
        const float* __restrict__ s_in, const float* __restrict__ s_out,
        const float* __restrict__ h_in, const float* __restrict__ h_out,
        const float* __restrict__ last_c, const unsigned short* __restrict__ wb,
        float* __restrict__ out) {
    __shared__ unsigned short Xl[4 * SEGSZ + 32];   // 77888 B -> 2 blocks/CU

    const int t     = threadIdx.x;
    const int lane  = t & 63;
    const int wid   = t >> 6;
    const int waveM = wid >> 1;   // 0..1
    const int waveN = wid & 1;    // 0..1
    const int lrow  = lane & 15;  // fragment row (A) / col (B)
    const int lko   = lane >> 4;  // k-group 0..3

    const float* Xseg[4] = {s_in, s_out, h_in, h_out};

    // zero the over-read slack (s5=4,lko=3 tail reads run past the array)
    if (t < 32) Xl[4 * SEGSZ + t] = 0;

    // ---- Phase 1: coalesced staging, fp32 -> bf16 ----
    // Per segment: 64 rows x 76 float2-slots (slot 75 = zero pad cols 150..151).
    // 64*76 = 4864 slots = 19 iters x 256 threads, exact.
#pragma unroll
    for (int seg = 0; seg < 4; seg++) {
        const float* __restrict__ Xp = Xseg[seg];
#pragma unroll
        for (int it = 0; it < 19; it++) {
            int s   = t + it * 256;       // 0..4863
            int row = s / 76;
            int c2  = s - row * 76;       // float2 col
            unsigned int packed = 0;
            if (c2 < 75) {
                int gr = blockIdx.x * BM + row;
                if (gr > NTOK - 1) gr = NTOK - 1;   // tail-block dup, masked later
                float2 v = *(const float2*)&Xp[(long)gr * H + 2 * c2];
                packed = (unsigned int)f2bf(v.x) | ((unsigned int)f2bf(v.y) << 16);
            }
            *(unsigned int*)&Xl[seg * SEGSZ + row * LROW + 2 * c2] = packed;
        }
    }

    __syncthreads();   // the only barrier

    // ---- Phase 2: K-loop, 4 segs x 5 steps of 32 ----
    f32x4 acc[2][5];
#pragma unroll
    for (int m = 0; m < 2; m++)
#pragma unroll
        for (int n = 0; n < 5; n++) acc[m][n] = (f32x4){0.f, 0.f, 0.f, 0.f};

    // B-frag bases (bf16 elem offsets into wb)
    long bbase[5];
#pragma unroll
    for (int n = 0; n < 5; n++)
        bbase[n] = (long)(waveN * 80 + n * 16 + lrow) * KTOT + lko * 8;

    const int arow0 = waveM * 32 + lrow;   // LDS row base for A frags

#pragma unroll
    for (int seg = 0; seg < 4; seg++) {
#pragma unroll
        for (int s5 = 0; s5 < 5; s5++) {
            const int kof = s5 * 32 + lko * 8;

            short8 bf[5];
#pragma unroll
            for (int n = 0; n < 5; n++)
                bf[n] = *(const short8*)&wb[bbase[n] + seg * KSEG + s5 * 32];

            short8 af[2];
#pragma unroll
            for (int m = 0; m < 2; m++)
                af[m] = *(const short8*)&Xl[seg * SEGSZ + (arow0 + m * 16) * LROW + kof];

#pragma unroll
            for (int m = 0; m < 2; m++)
#pragma unroll
                for (int n = 0; n < 5; n++)
                    acc[m][n] = __builtin_amdgcn_mfma_f32_16x16x32_bf16(af[m], bf[n], acc[m][n], 0, 0, 0);
        }
    }

    // ---- fused epilogue: g = sigmoid(pre); cell = g*lc + g*g; hid = g*tanh(cell)
    const int row0w = blockIdx.x * BM + waveM * 32;
#pragma unroll
    for (int m = 0; m < 2; m++) {
#pragma unroll
        for (int r = 0; r < 4; r++) {
            const int row = row0w + m * 16 + lko * 4 + r;
            if (row >= NTOK) continue;
            const long rb = (long)row * H;
#pragma unroll
            for (int n = 0; n < 5; n++) {
                const int col = waveN * 80 + n * 16 + lrow;
                if (col >= H) continue;
                float pre = acc[m][n][r];
                float e   = __expf(-pre);
                float g   = __builtin_amdgcn_rcpf(1.f + e);
                float lc  = last_c[rb + col];
                float cell = g * lc + g * g;
                float e2  = __expf(-2.f * cell);
                float th  = (1.f - e2) * __builtin_amdgcn_rcpf(1.f + e2);
                out[rb + col]          = g * th;
                out[OUTOFF + rb + col] = cell;
            }
        }
    }
}

extern "C" void kernel_launch(void* const* d_in, const int* in_sizes, int n_in,
                              void* d_out, int out_size, void* d_ws, size_t ws_size,
                              hipStream_t stream) {
    const float* s_in   = (const float*)d_in[0];
    const float* s_out  = (const float*)d_in[1];
    const float* h_in   = (const float*)d_in[2];
    const float* h_out  = (const float*)d_in[3];
    const float* last_c = (const float*)d_in[4];
    const float* w_in   = (const float*)d_in[5];
    const float* w_out  = (const float*)d_in[6];
    const float* u_in   = (const float*)d_in[7];
    const float* u_out  = (const float*)d_in[8];

    unsigned short* wb = (unsigned short*)d_ws;   // 160*640*2 = 204800 B
    float* out = (float*)d_out;

    prep_w<<<(160 * KTOT + 255) / 256, 256, 0, stream>>>(w_in, w_out, u_in, u_out, wb);

    const int nblocks = (NTOK + BM - 1) / BM;  // 1563
    lstm_fused<<<nblocks, 256, 0, stream>>>(s_in, s_out, h_in, h_out, last_c, wb, out);
}

// Round 6
// 257.161 us; speedup vs baseline: 1.0937x; 1.0937x over previous
//
#include <hip/hip_runtime.h>
#include <hip/hip_bf16.h>

typedef __attribute__((ext_vector_type(8))) short short8;
typedef __attribute__((ext_vector_type(4))) float f32x4;

#define NTOK   100000
#define H      150
#define KSEG   160        // padded per-matrix K in wb
#define KTOT   640        // 4 * KSEG
#define OUTOFF (NTOK * H)

__device__ __forceinline__ unsigned short f2bf(float f) {
    unsigned int u = __builtin_bit_cast(unsigned int, f);
    u = (u + 0x7FFFu + ((u >> 16) & 1u)) >> 16;   // RNE
    return (unsigned short)u;
}

__device__ __forceinline__ short cvt_bf16(float f) {
    __hip_bfloat16 b = __float2bfloat16(f);      // compiler emits v_cvt_pk_bf16_f32 pairs
    return __builtin_bit_cast(short, b);
}

// ---------------------------------------------------------------------------
// Prepass: pack 4x [150,150] fp32 weights into wb[c][k] bf16, c in [0,160),
// k in [0,640) stacked (w_in | w_out | u_in | u_out), zero-padded.
// wb[c][k] = W_seg[k%160][c]
// ---------------------------------------------------------------------------
__global__ void prep_w(const float* __restrict__ w_in, const float* __restrict__ w_out,
                       const float* __restrict__ u_in, const float* __restrict__ u_out,
                       unsigned short* __restrict__ wb) {
    int idx = blockIdx.x * 256 + threadIdx.x;
    if (idx >= 160 * KTOT) return;
    int c = idx / KTOT;
    int k = idx % KTOT;
    int seg = k / KSEG;
    int k2  = k % KSEG;
    float v = 0.0f;
    if (c < H && k2 < H) {
        const float* W = (seg == 0) ? w_in : (seg == 1) ? w_out : (seg == 2) ? u_in : u_out;
        v = W[k2 * H + c];
    }
    wb[idx] = f2bf(v);
}

// ---------------------------------------------------------------------------
// Main fused kernel: NO LDS, NO barriers. Each wave owns 16 token rows and
// the FULL 160 output cols. A operand (16 rows x 640 k, bf16) lives entirely
// in registers: 20 frags x 4 VGPR = 80 VGPR, loaded as 80 independent
// float2s (row = lane&15 is lane-private, k contiguous per lane).
// B frags stream from the 200KB L2-resident packed weight buffer.
// ---------------------------------------------------------------------------
__global__ __launch_bounds__(256, 2) void lstm_fused(
        const float* __restrict__ s_in, const float* __restrict__ s_out,
        const float* __restrict__ h_in, const float* __restrict__ h_out,
        const float* __restrict__ last_c, const unsigned short* __restrict__ wb,
        float* __restrict__ out) {
    const int t    = threadIdx.x;
    const int lane = t & 63;
    const int wid  = t >> 6;
    const int lrow = lane & 15;   // A row within frag / B+C col within frag
    const int lko  = lane >> 4;   // k-group 0..3 (8 elems) / C row-group
    const int row0 = blockIdx.x * 64 + wid * 16;   // wave's first token row

    const float* Xseg[4] = {s_in, s_out, h_in, h_out};

    // Lane's A row (clamped for tail block; OOB rows masked in epilogue)
    int ar = row0 + lrow;
    if (ar > NTOK - 1) ar = NTOK - 1;
    const long abase = (long)ar * H;

    // ---- Load ALL of A into registers (80 independent float2 loads) ----
    short8 af[20];
#pragma unroll
    for (int seg = 0; seg < 4; seg++) {
        const float* __restrict__ Xp = Xseg[seg] + abase;
#pragma unroll
        for (int s5 = 0; s5 < 5; s5++) {
            const int k2b = s5 * 32 + lko * 8;
            float xv[8];
            if (s5 < 4) {
                // k2b+7 <= 127 < 150: always in-row, 8B-aligned
#pragma unroll
                for (int j = 0; j < 8; j += 2) {
                    float2 v = *(const float2*)&Xp[k2b + j];
                    xv[j] = v.x; xv[j + 1] = v.y;
                }
            } else {
                // tail: k2 in [128,160); valid float2 iff k2 < 149
#pragma unroll
                for (int j = 0; j < 8; j += 2) {
                    int k2 = k2b + j;
                    float2 v = make_float2(0.f, 0.f);
                    if (k2 < H - 1) v = *(const float2*)&Xp[k2];
                    xv[j] = v.x; xv[j + 1] = v.y;
                }
            }
            short8 a8;
#pragma unroll
            for (int j = 0; j < 8; j++) a8[j] = cvt_bf16(xv[j]);
            af[seg * 5 + s5] = a8;
        }
    }

    // ---- B pointers: 10 col-frags, per-step offset folds into immediate ----
    const unsigned short* wpn[10];
#pragma unroll
    for (int n = 0; n < 10; n++)
        wpn[n] = wb + (long)(n * 16 + lrow) * KTOT + lko * 8;

    f32x4 acc[10];
#pragma unroll
    for (int n = 0; n < 10; n++) acc[n] = (f32x4){0.f, 0.f, 0.f, 0.f};

    // ---- 20 K-steps: 10 L2 weight loads + 10 MFMA each, no barriers ----
#pragma unroll
    for (int ks = 0; ks < 20; ks++) {
        short8 bf[10];
#pragma unroll
        for (int n = 0; n < 10; n++)
            bf[n] = *(const short8*)(wpn[n] + ks * 32);
#pragma unroll
        for (int n = 0; n < 10; n++)
            acc[n] = __builtin_amdgcn_mfma_f32_16x16x32_bf16(af[ks], bf[n], acc[n], 0, 0, 0);
    }

    // ---- fused epilogue: g = sigmoid(pre); cell = g*lc + g*g; hid = g*tanh(cell)
#pragma unroll
    for (int r = 0; r < 4; r++) {
        const int row = row0 + lko * 4 + r;
        if (row >= NTOK) continue;
        const long rb = (long)row * H;
#pragma unroll
        for (int n = 0; n < 10; n++) {
            const int col = n * 16 + lrow;
            if (col >= H) continue;
            float pre = acc[n][r];
            float e   = __expf(-pre);
            float g   = __builtin_amdgcn_rcpf(1.f + e);
            float lc  = last_c[rb + col];
            float cell = g * lc + g * g;
            float e2  = __expf(-2.f * cell);
            float th  = (1.f - e2) * __builtin_amdgcn_rcpf(1.f + e2);
            out[rb + col]          = g * th;
            out[OUTOFF + rb + col] = cell;
        }
    }
}

extern "C" void kernel_launch(void* const* d_in, const int* in_sizes, int n_in,
                              void* d_out, int out_size, void* d_ws, size_t ws_size,
                              hipStream_t stream) {
    const float* s_in   = (const float*)d_in[0];
    const float* s_out  = (const float*)d_in[1];
    const float* h_in   = (const float*)d_in[2];
    const float* h_out  = (const float*)d_in[3];
    const float* last_c = (const float*)d_in[4];
    const float* w_in   = (const float*)d_in[5];
    const float* w_out  = (const float*)d_in[6];
    const float* u_in   = (const float*)d_in[7];
    const float* u_out  = (const float*)d_in[8];

    unsigned short* wb = (unsigned short*)d_ws;   // 160*640*2 = 204800 B
    float* out = (float*)d_out;

    prep_w<<<(160 * KTOT + 255) / 256, 256, 0, stream>>>(w_in, w_out, u_in, u_out, wb);

    const int nblocks = (NTOK + 63) / 64;  // 1563, 4 waves each, 16 rows/wave
    lstm_fused<<<nblocks, 256, 0, stream>>>(s_in, s_out, h_in, h_out, last_c, wb, out);
}